// Round 17
// baseline (498.217 us; speedup 1.0000x reference)
//
#include <hip/hip_runtime.h>
#include <hip/hip_bf16.h>

#define B_ 256
#define T_ 32
#define F_ 128
#define H_ 128
#define NF 64
#define OH 31
#define OW 255
#define POS_TOTAL (OH*OW)      // 7905
#define N1 256
#define KT 248                 // blocks = 31 y x 8 xb

typedef __attribute__((ext_vector_type(8))) short bf16x8;
typedef __attribute__((ext_vector_type(4))) float f32x4;

__device__ __forceinline__ unsigned int cvtpk(float lo, float hi) {
    unsigned int r;
    asm("v_cvt_pk_bf16_f32 %0, %1, %2" : "=v"(r) : "v"(lo), "v"(hi));
    return r;
}

// ---------------- K1: attention -> featL [b=256][rc=8192] ----------------
__global__ __launch_bounds__(256) void k_attn(
    const float* __restrict__ X, const float* __restrict__ W,
    const float* __restrict__ U, const float* __restrict__ V,
    float* __restrict__ featL)
{
    __shared__ float Xs[T_][F_];
    __shared__ float xw[T_][H_];
    __shared__ float xu[T_][H_];
    __shared__ float sc[T_][T_];
    __shared__ float Vs[H_];

    const int b = blockIdx.x;
    const int t = threadIdx.x;
    const float* Xb = X + (size_t)b * T_ * F_;

    for (int idx = t; idx < T_*F_; idx += 256) ((float*)Xs)[idx] = Xb[idx];
    if (t < H_) Vs[t] = V[t];
    __syncthreads();

    {
        const int h = t & 127, half = t >> 7;
        float aw[16], au[16];
        #pragma unroll
        for (int r = 0; r < 16; r++) { aw[r] = 0.f; au[r] = 0.f; }
        for (int f = 0; f < F_; f++) {
            const float wv = W[f*H_ + h];
            const float uv = U[f*H_ + h];
            #pragma unroll
            for (int r = 0; r < 16; r++) {
                const float xv = Xs[half*16 + r][f];
                aw[r] += xv * wv;
                au[r] += xv * uv;
            }
        }
        #pragma unroll
        for (int r = 0; r < 16; r++) {
            xw[half*16 + r][h] = aw[r];
            xu[half*16 + r][h] = au[r];
        }
    }
    __syncthreads();

    {
        const int i = t >> 3;
        const int j0 = (t & 7) * 4;
        float s0 = 0.f, s1 = 0.f, s2 = 0.f, s3 = 0.f;
        for (int h = 0; h < H_; h++) {
            const float xwv = xw[i][h];
            const float vv  = Vs[h];
            s0 += tanhf(xwv + xu[j0+0][h]) * vv;
            s1 += tanhf(xwv + xu[j0+1][h]) * vv;
            s2 += tanhf(xwv + xu[j0+2][h]) * vv;
            s3 += tanhf(xwv + xu[j0+3][h]) * vv;
        }
        sc[i][j0+0] = s0; sc[i][j0+1] = s1; sc[i][j0+2] = s2; sc[i][j0+3] = s3;
    }
    __syncthreads();

    if (t < T_) {
        float m = -1e30f;
        #pragma unroll
        for (int j = 0; j < T_; j++) m = fmaxf(m, sc[t][j]);
        float sum = 0.f;
        #pragma unroll
        for (int j = 0; j < T_; j++) sum += expf(sc[t][j] - m);
        const float inv = 1.f / sum;
        #pragma unroll
        for (int j = 0; j < T_; j++) {
            const float a = expf(sc[t][j] - m) * inv;
            sc[t][j] = (j == t) ? 0.f : a;
        }
    }
    __syncthreads();

    for (int idx = t; idx < T_*F_; idx += 256) {
        const int row = idx >> 7, f = idx & 127;
        float acc = 0.f;
        #pragma unroll
        for (int j = 0; j < T_; j++) acc += sc[row][j] * Xs[j][f];
        float* fr = featL + (size_t)b*8192 + row*256;
        fr[f]       = Xs[row][f];
        fr[128 + f] = acc;
    }
}

// -------- K1b: transpose featL[b][rc] -> featT[rc][b], LDS-tiled --------
__global__ __launch_bounds__(256) void k_tr(
    const float* __restrict__ src, float* __restrict__ dst)
{
    __shared__ float tile[32][33];
    const int rc0 = blockIdx.x * 32;
    const int b0  = blockIdx.y * 32;
    const int tx = threadIdx.x & 31;
    const int ty = threadIdx.x >> 5;
    #pragma unroll
    for (int r = 0; r < 32; r += 8)
        tile[ty + r][tx] = src[(size_t)(b0 + ty + r)*8192 + rc0 + tx];
    __syncthreads();
    #pragma unroll
    for (int r = 0; r < 32; r += 8)
        dst[(size_t)(rc0 + ty + r)*256 + b0 + tx] = tile[tx][ty + r];
}

// ------- K2: fused conv + MFMA GEMM1 — R12 base, 4 As-buffers, 2 steps/barrier -------
// Grid 248 = (y = kt>>3, xb = kt&7). Tile 256x256, 32 steps of K=64 (2 filters
// x 32 pos). Waves 1m x 8n (wave tile 256x32): W direct global->VGPR (single
// set, 1-step slack); A conv-staged to LDS As[4] (128 KiB, XOR swizzle).
// One lgkm-only barrier per 2 steps; buffer indices all compile-time.
__global__ __launch_bounds__(512, 2) void k_gemm1(
    const float* __restrict__ featT, const float* __restrict__ cw,
    const float* __restrict__ cb, const float* __restrict__ w1,
    float* __restrict__ partial)
{
    __shared__ unsigned short As[4][256*64];   // 4 x 32 KiB
    __shared__ float cwL[256];
    __shared__ float cbL[64];

    const int t  = threadIdx.x;
    const int kt = blockIdx.x;
    const int y  = kt >> 3;
    const int x0 = (kt & 7) * 32;

    if (t < 256) cwL[t] = cw[t];
    if (t < 64)  cbL[t] = cb[t];

    // A-staging role: row rm, pos-half ph (16 pos each)
    const int rm = t & 255;
    const int ph = t >> 8;
    // MFMA role: 8 waves, 1m x 8n; wave tile 256x32
    const int lane = t & 63, wid = t >> 6;
    const int wn = wid * 32;
    const int fr = lane & 15, fq = lane >> 4;

    f32x4 acc[16][2];
    #pragma unroll
    for (int i = 0; i < 16; i++) {
        acc[i][0] = (f32x4){0.f, 0.f, 0.f, 0.f};
        acc[i][1] = (f32x4){0.f, 0.f, 0.f, 0.f};
    }

    // ---- block-constant conv patch: overlapping taps -> 2x17 regs ----
    float topv[17], botv[17];
    #pragma unroll
    for (int i = 0; i < 17; i++) {
        int xc = x0 + ph*16 + i; if (xc > 255) xc = 255;
        topv[i] = featT[((size_t)(y*256 + xc))*256 + rm];
        botv[i] = featT[((size_t)((y+1)*256 + xc))*256 + rm];
    }

    // ---- per-lane w1 element offsets (within one filter plane) ----
    int boff[8];
    #pragma unroll
    for (int j = 0; j < 8; j++) {
        int xc = x0 + fq*8 + j; if (xc > 254) xc = 254;   // clamped; A=0 kills it
        boff[j] = (y*255 + xc)*N1 + wn + fr;
    }

    float wv[2][2][8];   // [kc=filter][ng][j] — single set, refilled each step

    // W loads for step S (filters 2S, 2S+1), per-lane addresses
#define WLOAD(S)                                                               \
    {                                                                          \
        _Pragma("unroll")                                                      \
        for (int kc = 0; kc < 2; kc++) {                                       \
            const float* wf_ = w1 + (size_t)(2*(S) + kc) * (POS_TOTAL*N1);     \
            _Pragma("unroll")                                                  \
            for (int ng = 0; ng < 2; ng++)                                     \
                _Pragma("unroll")                                              \
                for (int j = 0; j < 8; j++)                                    \
                    wv[kc][ng][j] = wf_[boff[j] + ng*16];                      \
        }                                                                      \
    }

    // conv + bf16 + ds_write for step S into buffer BUF (2 filters)
#define STAGE(BUF, S)                                                          \
    {                                                                          \
        _Pragma("unroll")                                                      \
        for (int fl = 0; fl < 2; fl++) {                                       \
            const int f_ = 2*(S) + fl;                                         \
            const float4 cc_ = *(const float4*)&cwL[f_*4];                     \
            const float cbv_ = cbL[f_];                                        \
            unsigned int pk_[4];                                               \
            _Pragma("unroll")                                                  \
            for (int i2 = 0; i2 < 8; i2++) {                                   \
                const int i0 = 2*i2, i1 = 2*i2 + 1;                            \
                float v0_ = topv[i0]*cc_.x + topv[i0+1]*cc_.y                  \
                          + botv[i0]*cc_.z + botv[i0+1]*cc_.w + cbv_;          \
                float v1_ = topv[i1]*cc_.x + topv[i1+1]*cc_.y                  \
                          + botv[i1]*cc_.z + botv[i1+1]*cc_.w + cbv_;          \
                v0_ = (x0 + ph*16 + i0 < 255) ? fmaxf(v0_, 0.f) : 0.f;         \
                v1_ = (x0 + ph*16 + i1 < 255) ? fmaxf(v1_, 0.f) : 0.f;         \
                pk_[i2 & 3] = cvtpk(v0_, v1_);                                 \
                if ((i2 & 3) == 3) {                                           \
                    const int kb_ = fl*4 + ph*2 + (i2 >> 2);                   \
                    *(uint4*)&As[BUF][rm*64 + ((kb_ ^ (rm & 7))*8)]            \
                        = *(uint4*)&pk_[0];                                    \
                }                                                              \
            }                                                                  \
        }                                                                      \
    }

    // one step: convert wv -> B frags, refill wv for NEXTS, MFMA vs As[BUF]
#define STEP(BUF, NEXTS, DOLOAD)                                               \
    {                                                                          \
        bf16x8 bf[2][2];                                                       \
        _Pragma("unroll")                                                      \
        for (int kc = 0; kc < 2; kc++)                                         \
            _Pragma("unroll")                                                  \
            for (int ng = 0; ng < 2; ng++) {                                   \
                unsigned int* bu = (unsigned int*)&bf[kc][ng];                 \
                _Pragma("unroll")                                              \
                for (int q = 0; q < 4; q++)                                    \
                    bu[q] = cvtpk(wv[kc][ng][2*q], wv[kc][ng][2*q+1]);         \
            }                                                                  \
        if (DOLOAD) WLOAD(NEXTS);                                              \
        __builtin_amdgcn_s_setprio(1);                                         \
        _Pragma("unroll")                                                      \
        for (int kc = 0; kc < 2; kc++) {                                       \
            const int sw = ((kc*4 + fq) ^ (fr & 7)) * 8;                       \
            _Pragma("unroll")                                                  \
            for (int mg = 0; mg < 16; mg++) {                                  \
                const bf16x8 af =                                              \
                    *(const bf16x8*)&As[BUF][(mg*16 + fr)*64 + sw];            \
                acc[mg][0] = __builtin_amdgcn_mfma_f32_16x16x32_bf16(          \
                    af, bf[kc][0], acc[mg][0], 0, 0, 0);                       \
                acc[mg][1] = __builtin_amdgcn_mfma_f32_16x16x32_bf16(          \
                    af, bf[kc][1], acc[mg][1], 0, 0, 0);                       \
            }                                                                  \
        }                                                                      \
        __builtin_amdgcn_s_setprio(0);                                         \
    }

#define LB() do { asm volatile("s_waitcnt lgkmcnt(0)" ::: "memory"); \
                  __builtin_amdgcn_s_barrier(); } while (0)

    // ---- prologue: patch + W(0); stage steps 0,1 into bufs 0,1 ----
    WLOAD(0);
    __syncthreads();             // one-time full drain: cwL/cbL/patch/wv ready
    STAGE(0, 0);
    STAGE(1, 1);
    LB();

    // ---- steady state: 8 iters x 4 steps, 2 barriers/iter, static bufs ----
    #pragma unroll 1
    for (int g = 0; g < 8; g++) {
        const int S = 4*g;
        // window A: steps S (buf0), S+1 (buf1); stage bufs 2,3
        STEP(0, S+1, 1);
        STEP(1, S+2, (S+2 < 32));
        if (S+2 < 32) STAGE(2, S+2);
        if (S+3 < 32) STAGE(3, S+3);
        LB();
        if (S+2 >= 32) break;
        // window B: steps S+2 (buf2), S+3 (buf3); stage bufs 0,1
        STEP(2, S+3, 1);
        STEP(3, S+4, (S+4 < 32));
        if (S+4 < 32) STAGE(0, S+4);
        if (S+5 < 32) STAGE(1, S+5);
        LB();
    }

    // ---- write fp32 partial tile (256x256) ----
    float* pp = partial + (size_t)kt * (256*N1);
    #pragma unroll
    for (int mg = 0; mg < 16; mg++)
        #pragma unroll
        for (int ng = 0; ng < 2; ng++) {
            const int col = wn + ng*16 + fr;
            #pragma unroll
            for (int j = 0; j < 4; j++) {
                const int row = mg*16 + fq*4 + j;
                pp[(size_t)row*N1 + col] = acc[mg][ng][j];
            }
        }
#undef WLOAD
#undef STAGE
#undef STEP
#undef LB
}

// ------- K3: reduce partials + b1/relu + h@w2 relu + @w3 + b3 -------
__global__ __launch_bounds__(256) void k_head(
    const float* __restrict__ partial,
    const float* __restrict__ b1, const float* __restrict__ w2,
    const float* __restrict__ b2, const float* __restrict__ w3,
    const float* __restrict__ b3, float* __restrict__ out)
{
    __shared__ float h1s[256];
    __shared__ float h2s[32];
    const int b = blockIdx.x, t = threadIdx.x;

    const float* pb = partial + (size_t)b*N1 + t;
    float s0 = 0.f, s1 = 0.f, s2 = 0.f, s3 = 0.f;
    #pragma unroll 2
    for (int kt = 0; kt < KT; kt += 4) {
        s0 += pb[(size_t)(kt+0)*65536];
        s1 += pb[(size_t)(kt+1)*65536];
        s2 += pb[(size_t)(kt+2)*65536];
        s3 += pb[(size_t)(kt+3)*65536];
    }
    h1s[t] = fmaxf(b1[t] + ((s0+s1)+(s2+s3)), 0.f);
    __syncthreads();

    if (t < 32) {
        float s2v = b2[t];
        for (int i = 0; i < 256; i++) s2v += h1s[i] * w2[i*32 + t];
        h2s[t] = fmaxf(s2v, 0.f);
    }
    __syncthreads();

    if (t < 2) {
        float s3v = b3[t];
        #pragma unroll
        for (int i = 0; i < 32; i++) s3v += h2s[i] * w3[i*2 + t];
        out[b*2 + t] = s3v;
    }
}

extern "C" void kernel_launch(void* const* d_in, const int* in_sizes, int n_in,
                              void* d_out, int out_size, void* d_ws, size_t ws_size,
                              hipStream_t stream) {
    const float* X    = (const float*)d_in[0];
    const float* attW = (const float*)d_in[1];
    const float* attU = (const float*)d_in[2];
    const float* attV = (const float*)d_in[3];
    const float* cw   = (const float*)d_in[4];
    const float* cb   = (const float*)d_in[5];
    const float* w1   = (const float*)d_in[6];
    const float* b1   = (const float*)d_in[7];
    const float* w2   = (const float*)d_in[8];
    const float* b2   = (const float*)d_in[9];
    const float* w3   = (const float*)d_in[10];
    const float* b3   = (const float*)d_in[11];
    float* out = (float*)d_out;

    float* featL   = (float*)d_ws;                                   //  8 MB
    float* featT   = (float*)((char*)d_ws + (8u<<20));               //  8 MB
    float* partial = (float*)((char*)d_ws + (16u<<20));              // 62 MB

    k_attn <<<dim3(B_),       dim3(256), 0, stream>>>(X, attW, attU, attV, featL);
    k_tr   <<<dim3(256, 8),   dim3(256), 0, stream>>>(featL, featT);
    k_gemm1<<<dim3(KT),       dim3(512), 0, stream>>>(featT, cw, cb, w1, partial);
    k_head <<<dim3(B_),       dim3(256), 0, stream>>>(partial, b1, w2, b2, w3, b3, out);
}

// Round 18
// 260.307 us; speedup vs baseline: 1.9140x; 1.9140x over previous
//
#include <hip/hip_runtime.h>
#include <hip/hip_bf16.h>

#define B_ 256
#define T_ 32
#define F_ 128
#define H_ 128
#define NF 64
#define OH 31
#define OW 255
#define POS_TOTAL (OH*OW)      // 7905
#define N1 256
#define KT 248                 // blocks = 31 y x 8 xb

typedef __attribute__((ext_vector_type(8))) short bf16x8;
typedef __attribute__((ext_vector_type(4))) float f32x4;

__device__ __forceinline__ unsigned int cvtpk(float lo, float hi) {
    unsigned int r;
    asm("v_cvt_pk_bf16_f32 %0, %1, %2" : "=v"(r) : "v"(lo), "v"(hi));
    return r;
}

// ---------------- K1: attention -> featL [b=256][rc=8192] ----------------
__global__ __launch_bounds__(256) void k_attn(
    const float* __restrict__ X, const float* __restrict__ W,
    const float* __restrict__ U, const float* __restrict__ V,
    float* __restrict__ featL)
{
    __shared__ float Xs[T_][F_];
    __shared__ float xw[T_][H_];
    __shared__ float xu[T_][H_];
    __shared__ float sc[T_][T_];
    __shared__ float Vs[H_];

    const int b = blockIdx.x;
    const int t = threadIdx.x;
    const float* Xb = X + (size_t)b * T_ * F_;

    for (int idx = t; idx < T_*F_; idx += 256) ((float*)Xs)[idx] = Xb[idx];
    if (t < H_) Vs[t] = V[t];
    __syncthreads();

    {
        const int h = t & 127, half = t >> 7;
        float aw[16], au[16];
        #pragma unroll
        for (int r = 0; r < 16; r++) { aw[r] = 0.f; au[r] = 0.f; }
        for (int f = 0; f < F_; f++) {
            const float wv = W[f*H_ + h];
            const float uv = U[f*H_ + h];
            #pragma unroll
            for (int r = 0; r < 16; r++) {
                const float xv = Xs[half*16 + r][f];
                aw[r] += xv * wv;
                au[r] += xv * uv;
            }
        }
        #pragma unroll
        for (int r = 0; r < 16; r++) {
            xw[half*16 + r][h] = aw[r];
            xu[half*16 + r][h] = au[r];
        }
    }
    __syncthreads();

    {
        const int i = t >> 3;
        const int j0 = (t & 7) * 4;
        float s0 = 0.f, s1 = 0.f, s2 = 0.f, s3 = 0.f;
        for (int h = 0; h < H_; h++) {
            const float xwv = xw[i][h];
            const float vv  = Vs[h];
            s0 += tanhf(xwv + xu[j0+0][h]) * vv;
            s1 += tanhf(xwv + xu[j0+1][h]) * vv;
            s2 += tanhf(xwv + xu[j0+2][h]) * vv;
            s3 += tanhf(xwv + xu[j0+3][h]) * vv;
        }
        sc[i][j0+0] = s0; sc[i][j0+1] = s1; sc[i][j0+2] = s2; sc[i][j0+3] = s3;
    }
    __syncthreads();

    if (t < T_) {
        float m = -1e30f;
        #pragma unroll
        for (int j = 0; j < T_; j++) m = fmaxf(m, sc[t][j]);
        float sum = 0.f;
        #pragma unroll
        for (int j = 0; j < T_; j++) sum += expf(sc[t][j] - m);
        const float inv = 1.f / sum;
        #pragma unroll
        for (int j = 0; j < T_; j++) {
            const float a = expf(sc[t][j] - m) * inv;
            sc[t][j] = (j == t) ? 0.f : a;
        }
    }
    __syncthreads();

    for (int idx = t; idx < T_*F_; idx += 256) {
        const int row = idx >> 7, f = idx & 127;
        float acc = 0.f;
        #pragma unroll
        for (int j = 0; j < T_; j++) acc += sc[row][j] * Xs[j][f];
        float* fr = featL + (size_t)b*8192 + row*256;
        fr[f]       = Xs[row][f];
        fr[128 + f] = acc;
    }
}

// -------- K1b: transpose featL[b][rc] -> featT[rc][b], LDS-tiled --------
__global__ __launch_bounds__(256) void k_tr(
    const float* __restrict__ src, float* __restrict__ dst)
{
    __shared__ float tile[32][33];
    const int rc0 = blockIdx.x * 32;
    const int b0  = blockIdx.y * 32;
    const int tx = threadIdx.x & 31;
    const int ty = threadIdx.x >> 5;
    #pragma unroll
    for (int r = 0; r < 32; r += 8)
        tile[ty + r][tx] = src[(size_t)(b0 + ty + r)*8192 + rc0 + tx];
    __syncthreads();
    #pragma unroll
    for (int r = 0; r < 32; r += 8)
        dst[(size_t)(rc0 + ty + r)*256 + b0 + tx] = tile[tx][ty + r];
}

// ------- K2: fused conv + MFMA GEMM1 — W direct-to-register, 1-step slack -------
// Grid 248 = (y = kt>>3, xb = kt&7). Tile 256x256, 32 steps of K=64 (2 filters
// x 32 pos). Waves: 1m x 8n (wave tile 256x32) -> each wave loads its own
// B-fragments global->VGPR (w1 fetched once, no Ws LDS). As only in LDS
// (2 x 32 KiB, XOR-swizzled). One lgkm-only barrier per step.
__global__ __launch_bounds__(512, 2) void k_gemm1(
    const float* __restrict__ featT, const float* __restrict__ cw,
    const float* __restrict__ cb, const float* __restrict__ w1,
    float* __restrict__ partial)
{
    __shared__ unsigned short As[2][256*64];   // 2 x 32 KiB
    __shared__ float cwL[256];
    __shared__ float cbL[64];

    const int t  = threadIdx.x;
    const int kt = blockIdx.x;
    const int y  = kt >> 3;
    const int x0 = (kt & 7) * 32;

    if (t < 256) cwL[t] = cw[t];
    if (t < 64)  cbL[t] = cb[t];

    // A-staging role: row rm, pos-half ph (16 pos each)
    const int rm = t & 255;
    const int ph = t >> 8;
    // MFMA role: 8 waves, 1m x 8n; wave tile 256x32
    const int lane = t & 63, wid = t >> 6;
    const int wn = wid * 32;
    const int fr = lane & 15, fq = lane >> 4;

    f32x4 acc[16][2];
    #pragma unroll
    for (int i = 0; i < 16; i++) {
        acc[i][0] = (f32x4){0.f, 0.f, 0.f, 0.f};
        acc[i][1] = (f32x4){0.f, 0.f, 0.f, 0.f};
    }

    // ---- block-constant conv patch: overlapping taps -> 2x17 regs ----
    float topv[17], botv[17];
    #pragma unroll
    for (int i = 0; i < 17; i++) {
        int xc = x0 + ph*16 + i; if (xc > 255) xc = 255;
        topv[i] = featT[((size_t)(y*256 + xc))*256 + rm];
        botv[i] = featT[((size_t)((y+1)*256 + xc))*256 + rm];
    }

    // ---- per-lane w1 element offsets (within one filter plane) ----
    int poff[8];
    #pragma unroll
    for (int j = 0; j < 8; j++) {
        int xc = x0 + fq*8 + j; if (xc > 254) xc = 254;   // clamped; A=0 kills it
        poff[j] = (y*255 + xc)*N1 + wn + fr;
    }

    float wv[2][2][8];   // [kc=filter][ng][j] — single set, reissued each step

    // W loads for step S (filters 2S, 2S+1), per-lane addresses
#define WLOAD(S)                                                               \
    {                                                                          \
        _Pragma("unroll")                                                      \
        for (int kc = 0; kc < 2; kc++) {                                       \
            const float* wf_ = w1 + (size_t)(2*(S) + kc) * (POS_TOTAL*N1);     \
            _Pragma("unroll")                                                  \
            for (int ng = 0; ng < 2; ng++)                                     \
                _Pragma("unroll")                                              \
                for (int j = 0; j < 8; j++)                                    \
                    wv[kc][ng][j] = wf_[poff[j] + ng*16];                      \
        }                                                                      \
    }

    // conv + bf16 + ds_write for step S into buffer BUF (2 filters)
#define STAGE(BUF, S)                                                          \
    {                                                                          \
        _Pragma("unroll")                                                      \
        for (int fl = 0; fl < 2; fl++) {                                       \
            const int f_ = 2*(S) + fl;                                         \
            const float4 cc_ = *(const float4*)&cwL[f_*4];                     \
            const float cbv_ = cbL[f_];                                        \
            unsigned int pk_[4];                                               \
            _Pragma("unroll")                                                  \
            for (int i2 = 0; i2 < 8; i2++) {                                   \
                const int i0 = 2*i2, i1 = 2*i2 + 1;                            \
                float v0_ = topv[i0]*cc_.x + topv[i0+1]*cc_.y                  \
                          + botv[i0]*cc_.z + botv[i0+1]*cc_.w + cbv_;          \
                float v1_ = topv[i1]*cc_.x + topv[i1+1]*cc_.y                  \
                          + botv[i1]*cc_.z + botv[i1+1]*cc_.w + cbv_;          \
                v0_ = (x0 + ph*16 + i0 < 255) ? fmaxf(v0_, 0.f) : 0.f;         \
                v1_ = (x0 + ph*16 + i1 < 255) ? fmaxf(v1_, 0.f) : 0.f;         \
                pk_[i2 & 3] = cvtpk(v0_, v1_);                                 \
                if ((i2 & 3) == 3) {                                           \
                    const int kb_ = fl*4 + ph*2 + (i2 >> 2);                   \
                    *(uint4*)&As[BUF][rm*64 + ((kb_ ^ (rm & 7))*8)]            \
                        = *(uint4*)&pk_[0];                                    \
                }                                                              \
            }                                                                  \
        }                                                                      \
    }

    // ---- prologue ----
    WLOAD(0);
    __syncthreads();             // one-time full drain: cwL/cbL/patch/wv0 ready
    STAGE(0, 0);
    asm volatile("s_waitcnt lgkmcnt(0)" ::: "memory");
    __builtin_amdgcn_s_barrier();

    #pragma unroll 1
    for (int s = 0; s < 32; s++) {
        const int cur = s & 1;

        // convert W set(s) (issued a full step ago) -> bf16 frags
        bf16x8 bf[2][2];
        #pragma unroll
        for (int kc = 0; kc < 2; kc++)
            #pragma unroll
            for (int ng = 0; ng < 2; ng++) {
                unsigned int* bu = (unsigned int*)&bf[kc][ng];
                #pragma unroll
                for (int q = 0; q < 4; q++)
                    bu[q] = cvtpk(wv[kc][ng][2*q], wv[kc][ng][2*q+1]);
            }

        if (s < 31) WLOAD(s + 1);       // reissue freed regs; lands next step

        __builtin_amdgcn_s_setprio(1);
        #pragma unroll
        for (int kc = 0; kc < 2; kc++) {
            const int sw = ((kc*4 + fq) ^ (fr & 7)) * 8;
            #pragma unroll
            for (int mg = 0; mg < 16; mg++) {
                const bf16x8 af =
                    *(const bf16x8*)&As[cur][(mg*16 + fr)*64 + sw];
                acc[mg][0] = __builtin_amdgcn_mfma_f32_16x16x32_bf16(
                    af, bf[kc][0], acc[mg][0], 0, 0, 0);
                acc[mg][1] = __builtin_amdgcn_mfma_f32_16x16x32_bf16(
                    af, bf[kc][1], acc[mg][1], 0, 0, 0);
            }
        }
        __builtin_amdgcn_s_setprio(0);

        if (s < 31) STAGE(cur ^ 1, s + 1);
        asm volatile("s_waitcnt lgkmcnt(0)" ::: "memory");
        __builtin_amdgcn_s_barrier();
    }

    // ---- write fp32 partial tile (256x256) ----
    float* pp = partial + (size_t)kt * (256*N1);
    #pragma unroll
    for (int mg = 0; mg < 16; mg++)
        #pragma unroll
        for (int ng = 0; ng < 2; ng++) {
            const int col = wn + ng*16 + fr;
            #pragma unroll
            for (int j = 0; j < 4; j++) {
                const int row = mg*16 + fq*4 + j;
                pp[(size_t)row*N1 + col] = acc[mg][ng][j];
            }
        }
#undef WLOAD
#undef STAGE
}

// ------- K3: reduce partials + b1/relu + h@w2 relu + @w3 + b3 -------
__global__ __launch_bounds__(256) void k_head(
    const float* __restrict__ partial,
    const float* __restrict__ b1, const float* __restrict__ w2,
    const float* __restrict__ b2, const float* __restrict__ w3,
    const float* __restrict__ b3, float* __restrict__ out)
{
    __shared__ float h1s[256];
    __shared__ float h2s[32];
    const int b = blockIdx.x, t = threadIdx.x;

    const float* pb = partial + (size_t)b*N1 + t;
    float s0 = 0.f, s1 = 0.f, s2 = 0.f, s3 = 0.f;
    #pragma unroll 2
    for (int kt = 0; kt < KT; kt += 4) {
        s0 += pb[(size_t)(kt+0)*65536];
        s1 += pb[(size_t)(kt+1)*65536];
        s2 += pb[(size_t)(kt+2)*65536];
        s3 += pb[(size_t)(kt+3)*65536];
    }
    h1s[t] = fmaxf(b1[t] + ((s0+s1)+(s2+s3)), 0.f);
    __syncthreads();

    if (t < 32) {
        float s2v = b2[t];
        for (int i = 0; i < 256; i++) s2v += h1s[i] * w2[i*32 + t];
        h2s[t] = fmaxf(s2v, 0.f);
    }
    __syncthreads();

    if (t < 2) {
        float s3v = b3[t];
        #pragma unroll
        for (int i = 0; i < 32; i++) s3v += h2s[i] * w3[i*2 + t];
        out[b*2 + t] = s3v;
    }
}

extern "C" void kernel_launch(void* const* d_in, const int* in_sizes, int n_in,
                              void* d_out, int out_size, void* d_ws, size_t ws_size,
                              hipStream_t stream) {
    const float* X    = (const float*)d_in[0];
    const float* attW = (const float*)d_in[1];
    const float* attU = (const float*)d_in[2];
    const float* attV = (const float*)d_in[3];
    const float* cw   = (const float*)d_in[4];
    const float* cb   = (const float*)d_in[5];
    const float* w1   = (const float*)d_in[6];
    const float* b1   = (const float*)d_in[7];
    const float* w2   = (const float*)d_in[8];
    const float* b2   = (const float*)d_in[9];
    const float* w3   = (const float*)d_in[10];
    const float* b3   = (const float*)d_in[11];
    float* out = (float*)d_out;

    float* featL   = (float*)d_ws;                                   //  8 MB
    float* featT   = (float*)((char*)d_ws + (8u<<20));               //  8 MB
    float* partial = (float*)((char*)d_ws + (16u<<20));              // 62 MB

    k_attn <<<dim3(B_),       dim3(256), 0, stream>>>(X, attW, attU, attV, featL);
    k_tr   <<<dim3(256, 8),   dim3(256), 0, stream>>>(featL, featT);
    k_gemm1<<<dim3(KT),       dim3(512), 0, stream>>>(featT, cw, cb, w1, partial);
    k_head <<<dim3(B_),       dim3(256), 0, stream>>>(partial, b1, w2, b2, w3, b3, out);
}